// Round 22
// baseline (229.124 us; speedup 1.0000x reference)
//
#include <hip/hip_runtime.h>

#define DD   121
#define NHID 15
#define NBLK 5
#define KS   11
#define IW   4096
#define OW   2043

// DPP row-rotate add: v += rotate_within_16_lane_row(v, N). VALU-only reduce.
#define ROR_ADD(v, N)                                                         \
  v += __int_as_float(__builtin_amdgcn_update_dpp(                            \
      0, __float_as_int(v), 0x120 + (N), 0xF, 0xF, true))

// Packed staging: W1 direct; W2 as per-idx (m,a) pairs; b2 as (m,a) pairs.
__device__ __forceinline__ void stage_weights(
    float* W1d, float* W2d, float* b2d, float* b1d,
    const float* __restrict__ W1, const float* __restrict__ W2,
    const float* __restrict__ b2, const float* __restrict__ b1,
    int blk, int t0, int nt)
{
    const float* W1b = W1 + blk * NHID * DD;
    const float* W2b = W2 + blk * 2 * DD * NHID;
    const float* b2b = b2 + blk * 2 * DD;
    for (int i = t0; i < NHID * DD; i += nt) W1d[i] = W1b[i];   // [j*DD+idx]
    for (int k = t0; k < DD * NHID; k += nt) {
        const int idx = k / NHID, j = k - idx * NHID;
        W2d[idx*32 + 2*j]     = W2b[idx*NHID + j];         // m-weight
        W2d[idx*32 + 2*j + 1] = W2b[(DD + idx)*NHID + j];  // loga-weight
    }
    for (int i = t0; i < DD; i += nt) {
        W2d[i*32 + 30] = 0.f;                              // pad lane 15
        W2d[i*32 + 31] = 0.f;
        b2d[2*i]     = b2b[i];
        b2d[2*i + 1] = b2b[DD + i];
    }
    for (int i = t0; i < NHID; i += nt) b1d[i] = b1[blk*NHID + i];
}

// ---------------------------------------------------------------------------
// Flow inverse (MAF) + post-process. 2 waves: wave0 scans (lanes 0..15, DPP
// reduce, 4-slot named-register prefetch distance 4), wave1 stages next
// block's weights into the other LDS buffer. (unchanged from r11-r21)
// ---------------------------------------------------------------------------
__global__ __launch_bounds__(128) void flow_kernel(
    const float* __restrict__ kc,
    const float* __restrict__ W1, const float* __restrict__ b1,
    const float* __restrict__ W2, const float* __restrict__ b2,
    const float* __restrict__ lg, const float* __restrict__ beta,
    const float* __restrict__ mean, const float* __restrict__ var,
    float* __restrict__ kout)
{
    __shared__ float xs[DD];
    __shared__ float us[DD];
    __shared__ float W1s[2][NHID * DD];
    __shared__ float W2p[2][DD * 32];     // [idx*32 + 2j] = (m, a) pair
    __shared__ float b2p[2][DD * 2];      // [2*idx] = (m, a) pair
    __shared__ float b1s[2][16];

    const int tid  = threadIdx.x;
    const int wv   = tid >> 6;
    const int lane = tid & 63;

    stage_weights(W1s[0], W2p[0], b2p[0], b1s[0], W1, W2, b2, b1, NBLK - 1, tid, 128);
    if (tid < DD) xs[tid] = kc[tid];
    __syncthreads();

    for (int b = NBLK - 1; b >= 0; --b) {
        const int buf = (NBLK - 1 - b) & 1;
        if (wv == 1) {
            if (b > 0)
                stage_weights(W1s[buf^1], W2p[buf^1], b2p[buf^1], b1s[buf^1],
                              W1, W2, b2, b1, b - 1, lane, 64);
        } else {
            // BatchNorm inverse (eval): x = (x-beta)*exp(-lg)*sqrt(var+eps)+mean
            for (int i = lane; i < DD; i += 64) {
                float s = sqrtf(var[b*DD + i] + 1e-5f);
                us[i] = (xs[i] - beta[b*DD + i]) * __expf(-lg[b*DD + i]) * s + mean[b*DD + i];
            }
            const int evenb = ((b & 1) == 0);
            if (lane < 16) {
                const int j  = lane;
                const int jc = (j < NHID) ? j : (NHID - 1);   // clamp W1 row addr
                float pre_h = (j < NHID) ? b1s[buf][j] : 0.f;

                auto step = [&](int t, int iS, float2 wpS, float w1S, float uvS, float2 bpS) {
                    float h  = (j < t && j < NHID) ? fmaxf(pre_h, 0.f) : 0.f;
                    float pm = h * wpS.x;
                    float pa = h * wpS.y;
                    ROR_ADD(pm, 1); ROR_ADD(pa, 1);
                    ROR_ADD(pm, 2); ROR_ADD(pa, 2);
                    ROR_ADD(pm, 4); ROR_ADD(pa, 4);
                    ROR_ADD(pm, 8); ROR_ADD(pa, 8);
                    const float xv = fmaf(uvS, __expf(pa + bpS.y), pm + bpS.x);
                    if (j >= t && j < NHID) pre_h = fmaf(xv, w1S, pre_h);
                    if (j == 0) xs[iS] = xv;
                };

                int iA, iB, iC, iD;
                float2 wpA, wpB, wpC, wpD, bpA, bpB, bpC, bpD;
                float  w1A, w1B, w1C, w1D, uvA, uvB, uvC, uvD;

                #define PRELOAD(S, T) { const int tt = (T);                                 \
                    i##S  = evenb ? tt : (DD - 1 - tt);                                     \
                    wp##S = *(const float2*)&W2p[buf][i##S*32 + 2*j];                       \
                    w1##S = W1s[buf][jc*DD + i##S];                                         \
                    uv##S = us[i##S];                                                       \
                    bp##S = *(const float2*)&b2p[buf][2*i##S]; }

                #define QSTEP(S, TCUR, TNEXT) {                                             \
                    int tt = (TNEXT); if (tt > DD - 1) tt = DD - 1;                         \
                    const int ip = evenb ? tt : (DD - 1 - tt);                              \
                    const float2 wpN = *(const float2*)&W2p[buf][ip*32 + 2*j];              \
                    const float  w1N = W1s[buf][jc*DD + ip];                                \
                    const float  uvN = us[ip];                                              \
                    const float2 bpN = *(const float2*)&b2p[buf][2*ip];                     \
                    step((TCUR), i##S, wp##S, w1##S, uv##S, bp##S);                         \
                    i##S = ip; wp##S = wpN; w1##S = w1N; uv##S = uvN; bp##S = bpN; }

                PRELOAD(A, 0) PRELOAD(B, 1) PRELOAD(C, 2) PRELOAD(D, 3)
                #pragma unroll 1
                for (int it = 0; it < 30; ++it) {        // t = 4it .. 4it+3; DD-1=120=4*30
                    QSTEP(A, 4*it + 0, 4*it + 4)
                    QSTEP(B, 4*it + 1, 4*it + 5)
                    QSTEP(C, 4*it + 2, 4*it + 6)
                    QSTEP(D, 4*it + 3, 4*it + 7)
                }
                step(DD - 1, iA, wpA, w1A, uvA, bpA);    // final step t=120
                #undef PRELOAD
                #undef QSTEP
            }
        }
        __syncthreads();
    }

    // post-process: y = (sigmoid(x)-a)/(1-2a); k = y/sum(y)
    if (tid < 64) {
        const float A = 1e-6f;
        float y0, y1 = 0.f;
        {
            float v = xs[tid];
            y0 = (1.f / (1.f + __expf(-v)) - A) / (1.f - 2.f*A);
        }
        if (tid + 64 < DD) {
            float v = xs[tid + 64];
            y1 = (1.f / (1.f + __expf(-v)) - A) / (1.f - 2.f*A);
        }
        float s = y0 + y1;
        #pragma unroll
        for (int off = 32; off >= 1; off >>= 1) s += __shfl_xor(s, off, 64);
        kout[tid] = y0 / s;
        if (tid + 64 < DD) kout[tid + 64] = y1 / s;
    }
}

// ---------------------------------------------------------------------------
// COLUMN-SWEEP RING conv, CH=32 (r21 structure, doubled strip).
// Lane l owns 2 output cols; sweeps 32 output rows; 6-slot float2 ring.
// CH 16->32 cuts y-amplification 1.34->1.14 and ring-edge FMA waste 31%->14%
// (-13% total per-CU loads/lines/FMA) -- the r9-r21 ledger shows a ~160us
// wall invariant to occupancy/FETCH/conflicts/VGPR; only per-CU work remains.
// Per input ROW: 4 float4 loads at 16B lane stride (dense 1KB/instr) into one
// A/B slot. Ring: even row of pair t feeds ky=2a to slot (t-a)%6; odd row
// ky=2a+1 (a<5); output t-5 (slot (t+1)%6) completes after even row 2t.
// Packed float2 stores (c0 even -> 8B aligned). Clamps (word<=4092,
// row<=4095) corrupt only store-guarded outputs.
// ---------------------------------------------------------------------------
#define CH 32     // output rows per wave strip

__global__ __launch_bounds__(256) void conv_kernel(
    const float* __restrict__ in, const float* __restrict__ kf,
    float* __restrict__ out)
{
    const int tid = threadIdx.x;
    const int wv  = tid >> 6;                   // wave -> y-strip within block
    const int l   = tid & 63;
    const int bx  = blockIdx.x;                 // 0..15  (128-col span)
    const int by  = blockIdx.y;                 // 0..15  (4 strips each)
    const int ch  = blockIdx.z;
    const int sy  = by * 4 + wv;                // strip 0..63
    const int oy0 = sy * CH;
    const int gy0 = oy0 * 2;
    const int ox0 = bx * 128;
    const int c0  = ox0 + 2 * l;                // lane's first output col
    const int Wb  = 2 * ox0 + 4 * l;            // lane's input word base

    const float* __restrict__ inc  = in  + (size_t)ch * IW * IW;
    float*       __restrict__ outc = out + (size_t)ch * OW * OW;

    // clamped load bases (words); clamp affects only invalid-output lanes
    const int w0 = (Wb      <= 4092) ? Wb      : 4092;
    const int w1 = (Wb + 4  <= 4092) ? Wb + 4  : 4092;
    const int w2 = (Wb + 8  <= 4092) ? Wb + 8  : 4092;
    const int w3 = (Wb + 12 <= 4092) ? Wb + 12 : 4092;

    float2 acc[6] = {};

    float4 A0, A1, A2, A3;
    float4 B0, B1, B2, B3;

    #define LROW(R, S0, S1, S2, S3) {                                         \
        int gy_ = gy0 + (R); if (gy_ > IW - 1) gy_ = IW - 1;                  \
        const float* rp_ = inc + (size_t)gy_ * IW;                            \
        S0 = *(const float4*)(rp_ + w0);  S1 = *(const float4*)(rp_ + w1);    \
        S2 = *(const float4*)(rp_ + w2);  S3 = *(const float4*)(rp_ + w3); }

    #define CE(U, S0, S1, S2, S3) {   /* even row of pair t, U = t%6 */       \
        const float v[16] = {S0.x,S0.y,S0.z,S0.w, S1.x,S1.y,S1.z,S1.w,        \
                             S2.x,S2.y,S2.z,S2.w, S3.x,S3.y,S3.z,S3.w};       \
        _Pragma("unroll")                                                     \
        for (int a = 0; a < 6; ++a) {                                         \
            const int s = ((U) - a + 6) % 6;                                  \
            const float* kr = kf + (2*a) * KS;                                \
            _Pragma("unroll")                                                 \
            for (int kx = 0; kx < 11; ++kx) {                                 \
                const float w = kr[kx];                                       \
                acc[s].x = fmaf(v[kx],     w, acc[s].x);                      \
                acc[s].y = fmaf(v[kx + 2], w, acc[s].y);                      \
            }                                                                 \
        } }

    #define CO(U, S0, S1, S2, S3) {   /* odd row of pair t, U = t%6 */        \
        const float v[16] = {S0.x,S0.y,S0.z,S0.w, S1.x,S1.y,S1.z,S1.w,        \
                             S2.x,S2.y,S2.z,S2.w, S3.x,S3.y,S3.z,S3.w};       \
        _Pragma("unroll")                                                     \
        for (int a = 0; a < 5; ++a) {                                         \
            const int s = ((U) - a + 6) % 6;                                  \
            const float* kr = kf + (2*a + 1) * KS;                            \
            _Pragma("unroll")                                                 \
            for (int kx = 0; kx < 11; ++kx) {                                 \
                const float w = kr[kx];                                       \
                acc[s].x = fmaf(v[kx],     w, acc[s].x);                      \
                acc[s].y = fmaf(v[kx + 2], w, acc[s].y);                      \
            }                                                                 \
        } }

    #define ST(U, T) {                                                        \
        const int sc = ((U) + 1) % 6;                                         \
        if ((T) >= 5) {                                                       \
            const int oy = oy0 + (T) - 5;                                     \
            if (oy < OW) {                                                    \
                float* op = outc + (size_t)oy * OW + c0;                      \
                if (c0 + 1 < OW)      *(float2*)op = acc[sc];                 \
                else if (c0 < OW)     op[0] = acc[sc].x;                      \
            }                                                                 \
        }                                                                     \
        acc[sc].x = 0.f; acc[sc].y = 0.f; }

    // pair t: [load odd row 2t+1 -> B] [CE(A)=even row 2t] [store t-5]
    //         [load even row 2t+2 -> A] [CO(B)=odd row 2t+1]
    LROW(0, A0, A1, A2, A3)
    int t = 0;
    #pragma unroll 1
    for (int g = 0; g < 6; ++g) {                 // pairs t = 6g .. 6g+5 (0..35)
        LROW(2*t + 1, B0,B1,B2,B3)  CE(0, A0,A1,A2,A3)  ST(0, t)
        LROW(2*t + 2, A0,A1,A2,A3)  CO(0, B0,B1,B2,B3)  ++t;
        LROW(2*t + 1, B0,B1,B2,B3)  CE(1, A0,A1,A2,A3)  ST(1, t)
        LROW(2*t + 2, A0,A1,A2,A3)  CO(1, B0,B1,B2,B3)  ++t;
        LROW(2*t + 1, B0,B1,B2,B3)  CE(2, A0,A1,A2,A3)  ST(2, t)
        LROW(2*t + 2, A0,A1,A2,A3)  CO(2, B0,B1,B2,B3)  ++t;
        LROW(2*t + 1, B0,B1,B2,B3)  CE(3, A0,A1,A2,A3)  ST(3, t)
        LROW(2*t + 2, A0,A1,A2,A3)  CO(3, B0,B1,B2,B3)  ++t;
        LROW(2*t + 1, B0,B1,B2,B3)  CE(4, A0,A1,A2,A3)  ST(4, t)
        LROW(2*t + 2, A0,A1,A2,A3)  CO(4, B0,B1,B2,B3)  ++t;
        LROW(2*t + 1, B0,B1,B2,B3)  CE(5, A0,A1,A2,A3)  ST(5, t)
        LROW(2*t + 2, A0,A1,A2,A3)  CO(5, B0,B1,B2,B3)  ++t;
    }
    // epilogue: t=36 (U=0): even row 72 completes output oy0+31
    CE(0, A0,A1,A2,A3)  ST(0, t)

    #undef LROW
    #undef CE
    #undef CO
    #undef ST
}

extern "C" void kernel_launch(void* const* d_in, const int* in_sizes, int n_in,
                              void* d_out, int out_size, void* d_ws, size_t ws_size,
                              hipStream_t stream)
{
    const float* in   = (const float*)d_in[0];
    const float* kc   = (const float*)d_in[1];
    const float* W1   = (const float*)d_in[2];
    const float* b1   = (const float*)d_in[3];
    const float* W2   = (const float*)d_in[4];
    const float* b2   = (const float*)d_in[5];
    const float* lg   = (const float*)d_in[6];
    const float* beta = (const float*)d_in[7];
    const float* mean = (const float*)d_in[8];
    const float* var  = (const float*)d_in[9];

    float* out  = (float*)d_out;
    float* kout = out + (size_t)3 * OW * OW;   // out_k lives at the tail of d_out

    flow_kernel<<<dim3(1), dim3(128), 0, stream>>>(kc, W1, b1, W2, b2, lg, beta, mean, var, kout);

    dim3 grid(16, 16, 3);   // 16 x-spans x 16 y-groups (4 strips each) x 3 ch
    conv_kernel<<<grid, dim3(256), 0, stream>>>(in, kout, out);
}

// Round 23
// 190.319 us; speedup vs baseline: 1.2039x; 1.2039x over previous
//
#include <hip/hip_runtime.h>

#define DD   121
#define NHID 15
#define NBLK 5
#define KS   11
#define IW   4096
#define OW   2043

// DPP row-rotate add: v += rotate_within_16_lane_row(v, N). VALU-only reduce.
#define ROR_ADD(v, N)                                                         \
  v += __int_as_float(__builtin_amdgcn_update_dpp(                            \
      0, __float_as_int(v), 0x120 + (N), 0xF, 0xF, true))

// Packed staging: W1 direct; W2 as per-idx (m,a) pairs; b2 as (m,a) pairs.
__device__ __forceinline__ void stage_weights(
    float* W1d, float* W2d, float* b2d, float* b1d,
    const float* __restrict__ W1, const float* __restrict__ W2,
    const float* __restrict__ b2, const float* __restrict__ b1,
    int blk, int t0, int nt)
{
    const float* W1b = W1 + blk * NHID * DD;
    const float* W2b = W2 + blk * 2 * DD * NHID;
    const float* b2b = b2 + blk * 2 * DD;
    for (int i = t0; i < NHID * DD; i += nt) W1d[i] = W1b[i];   // [j*DD+idx]
    for (int k = t0; k < DD * NHID; k += nt) {
        const int idx = k / NHID, j = k - idx * NHID;
        W2d[idx*32 + 2*j]     = W2b[idx*NHID + j];         // m-weight
        W2d[idx*32 + 2*j + 1] = W2b[(DD + idx)*NHID + j];  // loga-weight
    }
    for (int i = t0; i < DD; i += nt) {
        W2d[i*32 + 30] = 0.f;                              // pad lane 15
        W2d[i*32 + 31] = 0.f;
        b2d[2*i]     = b2b[i];
        b2d[2*i + 1] = b2b[DD + i];
    }
    for (int i = t0; i < NHID; i += nt) b1d[i] = b1[blk*NHID + i];
}

// ---------------------------------------------------------------------------
// Flow inverse (MAF) + post-process. 2 waves: wave0 scans (lanes 0..15, DPP
// reduce, 4-slot named-register prefetch distance 4), wave1 stages next
// block's weights into the other LDS buffer. (unchanged from r11-r22)
// ---------------------------------------------------------------------------
__global__ __launch_bounds__(128) void flow_kernel(
    const float* __restrict__ kc,
    const float* __restrict__ W1, const float* __restrict__ b1,
    const float* __restrict__ W2, const float* __restrict__ b2,
    const float* __restrict__ lg, const float* __restrict__ beta,
    const float* __restrict__ mean, const float* __restrict__ var,
    float* __restrict__ kout)
{
    __shared__ float xs[DD];
    __shared__ float us[DD];
    __shared__ float W1s[2][NHID * DD];
    __shared__ float W2p[2][DD * 32];     // [idx*32 + 2j] = (m, a) pair
    __shared__ float b2p[2][DD * 2];      // [2*idx] = (m, a) pair
    __shared__ float b1s[2][16];

    const int tid  = threadIdx.x;
    const int wv   = tid >> 6;
    const int lane = tid & 63;

    stage_weights(W1s[0], W2p[0], b2p[0], b1s[0], W1, W2, b2, b1, NBLK - 1, tid, 128);
    if (tid < DD) xs[tid] = kc[tid];
    __syncthreads();

    for (int b = NBLK - 1; b >= 0; --b) {
        const int buf = (NBLK - 1 - b) & 1;
        if (wv == 1) {
            if (b > 0)
                stage_weights(W1s[buf^1], W2p[buf^1], b2p[buf^1], b1s[buf^1],
                              W1, W2, b2, b1, b - 1, lane, 64);
        } else {
            // BatchNorm inverse (eval): x = (x-beta)*exp(-lg)*sqrt(var+eps)+mean
            for (int i = lane; i < DD; i += 64) {
                float s = sqrtf(var[b*DD + i] + 1e-5f);
                us[i] = (xs[i] - beta[b*DD + i]) * __expf(-lg[b*DD + i]) * s + mean[b*DD + i];
            }
            const int evenb = ((b & 1) == 0);
            if (lane < 16) {
                const int j  = lane;
                const int jc = (j < NHID) ? j : (NHID - 1);   // clamp W1 row addr
                float pre_h = (j < NHID) ? b1s[buf][j] : 0.f;

                auto step = [&](int t, int iS, float2 wpS, float w1S, float uvS, float2 bpS) {
                    float h  = (j < t && j < NHID) ? fmaxf(pre_h, 0.f) : 0.f;
                    float pm = h * wpS.x;
                    float pa = h * wpS.y;
                    ROR_ADD(pm, 1); ROR_ADD(pa, 1);
                    ROR_ADD(pm, 2); ROR_ADD(pa, 2);
                    ROR_ADD(pm, 4); ROR_ADD(pa, 4);
                    ROR_ADD(pm, 8); ROR_ADD(pa, 8);
                    const float xv = fmaf(uvS, __expf(pa + bpS.y), pm + bpS.x);
                    if (j >= t && j < NHID) pre_h = fmaf(xv, w1S, pre_h);
                    if (j == 0) xs[iS] = xv;
                };

                int iA, iB, iC, iD;
                float2 wpA, wpB, wpC, wpD, bpA, bpB, bpC, bpD;
                float  w1A, w1B, w1C, w1D, uvA, uvB, uvC, uvD;

                #define PRELOAD(S, T) { const int tt = (T);                                 \
                    i##S  = evenb ? tt : (DD - 1 - tt);                                     \
                    wp##S = *(const float2*)&W2p[buf][i##S*32 + 2*j];                       \
                    w1##S = W1s[buf][jc*DD + i##S];                                         \
                    uv##S = us[i##S];                                                       \
                    bp##S = *(const float2*)&b2p[buf][2*i##S]; }

                #define QSTEP(S, TCUR, TNEXT) {                                             \
                    int tt = (TNEXT); if (tt > DD - 1) tt = DD - 1;                         \
                    const int ip = evenb ? tt : (DD - 1 - tt);                              \
                    const float2 wpN = *(const float2*)&W2p[buf][ip*32 + 2*j];              \
                    const float  w1N = W1s[buf][jc*DD + ip];                                \
                    const float  uvN = us[ip];                                              \
                    const float2 bpN = *(const float2*)&b2p[buf][2*ip];                     \
                    step((TCUR), i##S, wp##S, w1##S, uv##S, bp##S);                         \
                    i##S = ip; wp##S = wpN; w1##S = w1N; uv##S = uvN; bp##S = bpN; }

                PRELOAD(A, 0) PRELOAD(B, 1) PRELOAD(C, 2) PRELOAD(D, 3)
                #pragma unroll 1
                for (int it = 0; it < 30; ++it) {        // t = 4it .. 4it+3; DD-1=120=4*30
                    QSTEP(A, 4*it + 0, 4*it + 4)
                    QSTEP(B, 4*it + 1, 4*it + 5)
                    QSTEP(C, 4*it + 2, 4*it + 6)
                    QSTEP(D, 4*it + 3, 4*it + 7)
                }
                step(DD - 1, iA, wpA, w1A, uvA, bpA);    // final step t=120
                #undef PRELOAD
                #undef QSTEP
            }
        }
        __syncthreads();
    }

    // post-process: y = (sigmoid(x)-a)/(1-2a); k = y/sum(y)
    if (tid < 64) {
        const float A = 1e-6f;
        float y0, y1 = 0.f;
        {
            float v = xs[tid];
            y0 = (1.f / (1.f + __expf(-v)) - A) / (1.f - 2.f*A);
        }
        if (tid + 64 < DD) {
            float v = xs[tid + 64];
            y1 = (1.f / (1.f + __expf(-v)) - A) / (1.f - 2.f*A);
        }
        float s = y0 + y1;
        #pragma unroll
        for (int off = 32; off >= 1; off >>= 1) s += __shfl_xor(s, off, 64);
        kout[tid] = y0 / s;
        if (tid + 64 < DD) kout[tid + 64] = y1 / s;
    }
}

// ---------------------------------------------------------------------------
// COLUMN-SWEEP RING 11x11 stride-2 conv (r20 configuration — session best,
// total 189.46us). No LDS, no barriers, conflicts 0, FETCH ~140MB.
// Lane l owns 2 output cols c0=ox0+2l, c0+1 and sweeps 16 output rows.
// Per input-row PAIR: 8 float4 loads at 16B lane stride (coalesced 1KB/instr).
// 6-slot per-lane ring accumulator (float2 x 6, static idx via 6-unroll):
// pair t's even row feeds ky=2a to slots (t-a)%6 (a=0..5), odd row ky=2a+1
// (a=0..4); slot (t+1)%6 completes output row oy0+t-5 each pair.
// Clamps: load word base <= 4092, row <= 4095 -- corrupt only store-guarded
// outputs. 2-deep named A/B pair prefetch, unroll-1 outer.
// NOTE (r9-r22 ledger): conv wall ~155-165us is invariant to occupancy
// (21-75%), FETCH (104-334MB), conflicts (0-47M), VGPR (32-108); CH=32
// (r22) and wide pipelines (r10) regress via VGPR pressure. This config is
// the measured Pareto optimum of 10 structural variants.
// ---------------------------------------------------------------------------
#define CH 16     // output rows per wave strip

__global__ __launch_bounds__(256) void conv_kernel(
    const float* __restrict__ in, const float* __restrict__ kf,
    float* __restrict__ out)
{
    const int tid = threadIdx.x;
    const int wv  = tid >> 6;                   // wave -> y-strip within block
    const int l   = tid & 63;
    const int bx  = blockIdx.x;                 // 0..15  (128-col span)
    const int by  = blockIdx.y;                 // 0..31  (4 strips each)
    const int ch  = blockIdx.z;
    const int sy  = by * 4 + wv;                // strip 0..127
    const int oy0 = sy * CH;
    const int gy0 = oy0 * 2;
    const int ox0 = bx * 128;
    const int c0  = ox0 + 2 * l;                // lane's first output col
    const int Wb  = 2 * ox0 + 4 * l;            // lane's input word base

    const float* __restrict__ inc  = in  + (size_t)ch * IW * IW;
    float*       __restrict__ outc = out + (size_t)ch * OW * OW;

    // clamped load bases (words); clamp affects only invalid-output lanes
    const int w0 = (Wb      <= 4092) ? Wb      : 4092;
    const int w1 = (Wb + 4  <= 4092) ? Wb + 4  : 4092;
    const int w2 = (Wb + 8  <= 4092) ? Wb + 8  : 4092;
    const int w3 = (Wb + 12 <= 4092) ? Wb + 12 : 4092;

    float2 acc[6] = {};

    float4 Ae0, Ae1, Ae2, Ae3, Ao0, Ao1, Ao2, Ao3;
    float4 Be0, Be1, Be2, Be3, Bo0, Bo1, Bo2, Bo3;

    #define LDPAIR(T, E0,E1,E2,E3, O0,O1,O2,O3) {                             \
        int gye = gy0 + 2*(T);     if (gye > IW-1) gye = IW-1;                \
        int gyo = gy0 + 2*(T) + 1; if (gyo > IW-1) gyo = IW-1;                \
        const float* re = inc + (size_t)gye * IW;                             \
        const float* ro = inc + (size_t)gyo * IW;                             \
        E0 = *(const float4*)(re + w0);  E1 = *(const float4*)(re + w1);      \
        E2 = *(const float4*)(re + w2);  E3 = *(const float4*)(re + w3);      \
        O0 = *(const float4*)(ro + w0);  O1 = *(const float4*)(ro + w1);      \
        O2 = *(const float4*)(ro + w2);  O3 = *(const float4*)(ro + w3); }

    #define PAIRC(U, E0,E1,E2,E3, O0,O1,O2,O3) {                              \
        const float ev[16] = {E0.x,E0.y,E0.z,E0.w, E1.x,E1.y,E1.z,E1.w,       \
                              E2.x,E2.y,E2.z,E2.w, E3.x,E3.y,E3.z,E3.w};      \
        const float ov[16] = {O0.x,O0.y,O0.z,O0.w, O1.x,O1.y,O1.z,O1.w,       \
                              O2.x,O2.y,O2.z,O2.w, O3.x,O3.y,O3.z,O3.w};      \
        _Pragma("unroll")                                                     \
        for (int a = 0; a < 6; ++a) {             /* even row: ky = 2a */     \
            const int s = ((U) - a + 6) % 6;                                  \
            const float* kr = kf + (2*a) * KS;                                \
            _Pragma("unroll")                                                 \
            for (int kx = 0; kx < 11; ++kx) {                                 \
                const float w = kr[kx];                                       \
                acc[s].x = fmaf(ev[kx],     w, acc[s].x);                     \
                acc[s].y = fmaf(ev[kx + 2], w, acc[s].y);                     \
            }                                                                 \
        }                                                                     \
        _Pragma("unroll")                                                     \
        for (int a = 0; a < 5; ++a) {             /* odd row: ky = 2a+1 */    \
            const int s = ((U) - a + 6) % 6;                                  \
            const float* kr = kf + (2*a + 1) * KS;                            \
            _Pragma("unroll")                                                 \
            for (int kx = 0; kx < 11; ++kx) {                                 \
                const float w = kr[kx];                                       \
                acc[s].x = fmaf(ov[kx],     w, acc[s].x);                     \
                acc[s].y = fmaf(ov[kx + 2], w, acc[s].y);                     \
            }                                                                 \
        } }

    #define STORE(U, T) {                                                     \
        const int sc = ((U) + 1) % 6;                                         \
        if ((T) >= 5) {                                                       \
            const int oy = oy0 + (T) - 5;                                     \
            if (oy < OW) {                                                    \
                float* op = outc + (size_t)oy * OW + c0;                      \
                if (c0 < OW)     op[0] = acc[sc].x;                           \
                if (c0 + 1 < OW) op[1] = acc[sc].y;                           \
            }                                                                 \
        }                                                                     \
        acc[sc].x = 0.f; acc[sc].y = 0.f; }

    LDPAIR(0, Ae0,Ae1,Ae2,Ae3, Ao0,Ao1,Ao2,Ao3)
    int t = 0;
    #pragma unroll 1
    for (int g = 0; g < 3; ++g) {                 // pairs 0..17
        LDPAIR(t+1, Be0,Be1,Be2,Be3, Bo0,Bo1,Bo2,Bo3)
        PAIRC(0, Ae0,Ae1,Ae2,Ae3, Ao0,Ao1,Ao2,Ao3)  STORE(0, t)  ++t;
        LDPAIR(t+1, Ae0,Ae1,Ae2,Ae3, Ao0,Ao1,Ao2,Ao3)
        PAIRC(1, Be0,Be1,Be2,Be3, Bo0,Bo1,Bo2,Bo3)  STORE(1, t)  ++t;
        LDPAIR(t+1, Be0,Be1,Be2,Be3, Bo0,Bo1,Bo2,Bo3)
        PAIRC(2, Ae0,Ae1,Ae2,Ae3, Ao0,Ao1,Ao2,Ao3)  STORE(2, t)  ++t;
        LDPAIR(t+1, Ae0,Ae1,Ae2,Ae3, Ao0,Ao1,Ao2,Ao3)
        PAIRC(3, Be0,Be1,Be2,Be3, Bo0,Bo1,Bo2,Bo3)  STORE(3, t)  ++t;
        LDPAIR(t+1, Be0,Be1,Be2,Be3, Bo0,Bo1,Bo2,Bo3)
        PAIRC(4, Ae0,Ae1,Ae2,Ae3, Ao0,Ao1,Ao2,Ao3)  STORE(4, t)  ++t;
        LDPAIR(t+1, Ae0,Ae1,Ae2,Ae3, Ao0,Ao1,Ao2,Ao3)
        PAIRC(5, Be0,Be1,Be2,Be3, Bo0,Bo1,Bo2,Bo3)  STORE(5, t)  ++t;
    }
    // epilogue: pairs 18 (u=0, in A), 19 (u=1, in B), 20 (u=2, in A)
    LDPAIR(t+1, Be0,Be1,Be2,Be3, Bo0,Bo1,Bo2,Bo3)
    PAIRC(0, Ae0,Ae1,Ae2,Ae3, Ao0,Ao1,Ao2,Ao3)  STORE(0, t)  ++t;
    LDPAIR(t+1, Ae0,Ae1,Ae2,Ae3, Ao0,Ao1,Ao2,Ao3)
    PAIRC(1, Be0,Be1,Be2,Be3, Bo0,Bo1,Bo2,Bo3)  STORE(1, t)  ++t;
    PAIRC(2, Ae0,Ae1,Ae2,Ae3, Ao0,Ao1,Ao2,Ao3)  STORE(2, t)

    #undef LDPAIR
    #undef PAIRC
    #undef STORE
}

extern "C" void kernel_launch(void* const* d_in, const int* in_sizes, int n_in,
                              void* d_out, int out_size, void* d_ws, size_t ws_size,
                              hipStream_t stream)
{
    const float* in   = (const float*)d_in[0];
    const float* kc   = (const float*)d_in[1];
    const float* W1   = (const float*)d_in[2];
    const float* b1   = (const float*)d_in[3];
    const float* W2   = (const float*)d_in[4];
    const float* b2   = (const float*)d_in[5];
    const float* lg   = (const float*)d_in[6];
    const float* beta = (const float*)d_in[7];
    const float* mean = (const float*)d_in[8];
    const float* var  = (const float*)d_in[9];

    float* out  = (float*)d_out;
    float* kout = out + (size_t)3 * OW * OW;   // out_k lives at the tail of d_out

    flow_kernel<<<dim3(1), dim3(128), 0, stream>>>(kc, W1, b1, W2, b2, lg, beta, mean, var, kout);

    dim3 grid(16, 32, 3);   // 16 x-spans x 32 y-groups (4 strips each) x 3 ch
    conv_kernel<<<grid, dim3(256), 0, stream>>>(in, kout, out);
}